// Round 15
// baseline (1310.979 us; speedup 1.0000x reference)
//
#include <hip/hip_runtime.h>
#include <math.h>

// WaveNet forward, round 13: micro-cuts to the singles.
// - Round-12 postmortem: 1053.8 us (best). Singles (18 x ~33 us = 594 us)
//   dominate, at ~2.5x their 13.3 us traffic floor; stackA verified stable.
// - Change 1: hoist the chunk-RMW read in layer_kernel to kernel entry.
//   Compiler can't move global loads across __syncthreads, so the skip phase
//   was eating a full dependent-load stall. +16 VGPR (32->~48, under the
//   64 cap of launch_bounds(512,8) - no spill).
// - Change 2: template<LAST> layer_kernel skips the dead res GEMM + h store
//   on l=29 (h29 never read; head reads only chunk). -33.5 MB writes.
// - stackA (d=1,2,4,8 fused, waves_per_eu(2,4)) and head unchanged.
// - Coop/grid.sync stays deleted (5x regression, round 4).
//
// MFMA 16x16x32_f16: A lane: A[m=lane&15][k=(lane>>4)*8+j]; D lane:
// D[row=(lane>>4)*4+reg][col=lane&15]. Conv A-rows interleaved (a0,b0,a1,b1..)
// so GLU happens in registers. Conv K order: k = tap*128 + c.

#define NB 4
#define WLEN 16384
#define C 128
#define S 256
#define NLAYERS 30
#define TT 64
#define NTB (WLEN / TT)   // 256 tiles per sample
#define XROW 264          // head X row stride (f16): 256 + 8 pad
#define GROW 136          // single-layer tile row stride (f16): 128 + 8 pad

// swizzled f16 index into a pad-free 128-col row (stack kernel only)
#define SX(row, c) ((row) * 128 + ((c) ^ (((row) & 7) << 3)))

typedef _Float16 half8 __attribute__((ext_vector_type(8)));
typedef _Float16 half4 __attribute__((ext_vector_type(4)));
typedef float floatx4 __attribute__((ext_vector_type(4)));

__device__ __forceinline__ float sigmoidf_(float v) {
    return 1.0f / (1.0f + __expf(-v));
}

// ---------------- weight packing (unchanged layouts) ----------------
__global__ void prep_kernel(const float* __restrict__ conv_w,
                            const float* __restrict__ res_w,
                            const float* __restrict__ skip_w,
                            const float* __restrict__ a_w,
                            const float* __restrict__ b_w,
                            const float* __restrict__ conv_b,
                            const float* __restrict__ skip_b,
                            _Float16* __restrict__ cw,
                            _Float16* __restrict__ rsw,
                            _Float16* __restrict__ skw,
                            _Float16* __restrict__ aw,
                            _Float16* __restrict__ bw,
                            float* __restrict__ cbp,
                            float* __restrict__ ssum) {
    const int ncw = NLAYERS * 256 * 256;
    const int nrs = NLAYERS * 128 * 128;
    const int nsk = NLAYERS * 256 * 128;
    const int nab = 256 * 256;
    const int ncb = NLAYERS * 256;
    const int total = ncw + nrs + nsk + nab + nab + ncb + 256;
    for (int idx = blockIdx.x * blockDim.x + threadIdx.x; idx < total;
         idx += gridDim.x * blockDim.x) {
        int i = idx;
        if (i < ncw) {
            int j = i & 7, lane = (i >> 3) & 63, rest = i >> 9;
            int ks = rest & 7; rest >>= 3;
            int mt = rest & 15; int l = rest >> 4;
            int mp = mt * 16 + (lane & 15);
            int orow = (mp >> 1) + (mp & 1) * 128;
            int k = ks * 32 + (lane >> 4) * 8 + j;
            int tap = k >> 7, c = k & 127;
            cw[i] = (_Float16)conv_w[(((size_t)l * 256 + orow) * 128 + c) * 2 + tap];
        } else if (i < ncw + nrs) {
            i -= ncw;
            int j = i & 7, lane = (i >> 3) & 63, rest = i >> 9;
            int ks = rest & 3; rest >>= 2;
            int mt = rest & 7; int l = rest >> 3;
            int m = mt * 16 + (lane & 15);
            int k = ks * 32 + (lane >> 4) * 8 + j;
            rsw[i] = (_Float16)res_w[((size_t)l * 128 + m) * 128 + k];
        } else if (i < ncw + nrs + nsk) {
            i -= ncw + nrs;
            int j = i & 7, lane = (i >> 3) & 63, rest = i >> 9;
            int ks = rest & 3; rest >>= 2;
            int mt = rest & 15; int l = rest >> 4;
            int m = mt * 16 + (lane & 15);
            int k = ks * 32 + (lane >> 4) * 8 + j;
            skw[i] = (_Float16)skip_w[((size_t)l * 256 + m) * 128 + k];
        } else if (i < ncw + nrs + nsk + nab) {
            i -= ncw + nrs + nsk;
            int j = i & 7, lane = (i >> 3) & 63, rest = i >> 9;
            int ks = rest & 7; int mt = rest >> 3;
            aw[i] = (_Float16)a_w[(mt * 16 + (lane & 15)) * 256 + ks * 32 + (lane >> 4) * 8 + j];
        } else if (i < ncw + nrs + nsk + 2 * nab) {
            i -= ncw + nrs + nsk + nab;
            int j = i & 7, lane = (i >> 3) & 63, rest = i >> 9;
            int ks = rest & 7; int mt = rest >> 3;
            bw[i] = (_Float16)b_w[(mt * 16 + (lane & 15)) * 256 + ks * 32 + (lane >> 4) * 8 + j];
        } else if (i < ncw + nrs + nsk + 2 * nab + ncb) {
            i -= ncw + nrs + nsk + 2 * nab;
            int mp = i & 255; int l = i >> 8;
            cbp[i] = conv_b[l * 256 + (mp >> 1) + (mp & 1) * 128];
        } else {
            i -= ncw + nrs + nsk + 2 * nab + ncb;
            float s = 0.f;
            for (int l = 0; l < NLAYERS; ++l) s += skip_b[l * 256 + i];
            ssum[i] = s;
        }
    }
}

// ---------------- front: h0 (f16, [n][t][c]) ----------------
__global__ void front_kernel(const float* __restrict__ x,
                             const float* __restrict__ w_shift,
                             const float* __restrict__ b_shift,
                             _Float16* __restrict__ h) {
    const int n = blockIdx.y;
    const int t = blockIdx.x * 256 + threadIdx.x;
    float x1 = (t >= 1) ? x[n * WLEN + t - 1] : 0.0f;
    float x2 = (t >= 2) ? x[n * WLEN + t - 2] : 0.0f;
    _Float16* hq = h + ((size_t)n * WLEN + t) * 128;
    #pragma unroll
    for (int c0 = 0; c0 < 128; c0 += 8) {
        half8 v;
        #pragma unroll
        for (int j = 0; j < 8; ++j) {
            int c = c0 + j;
            v[j] = (_Float16)fmaf(w_shift[2 * c], x2,
                                  fmaf(w_shift[2 * c + 1], x1, b_shift[c]));
        }
        *(half8*)&hq[c0] = v;
    }
}

// ---------------- fused stack kernel (d=1,2,4,8 only) ----------------
// Window rows w=0..79 map to t = t0-16+w. Valid rows 16..79 = t0..t0+63.
// All 5 row-tiles computed uniformly; tap0 row clamped to >=0. LDS pad-free
// + XOR swizzle (SX). amdgpu_waves_per_eu(2,4): firm 128-VGPR budget, no
// spill (round-11/12 verified: VGPR 112, FETCH 35.7MB, WRITE 49MB).
template <int E0, int NL, int NT, int HALO, bool FIRST>
__global__ __launch_bounds__(512)
__attribute__((amdgpu_waves_per_eu(2, 4))) void stack_kernel(
    const _Float16* __restrict__ h_in, _Float16* __restrict__ h_out,
    _Float16* __restrict__ chunk,
    const _Float16* __restrict__ cw0, const float* __restrict__ cb0,
    const _Float16* __restrict__ rsw0, const float* __restrict__ rb0,
    const _Float16* __restrict__ skw0, const float* __restrict__ ssum) {
    constexpr int WR = NT * 16;
    __shared__ _Float16 SMEM[2 * WR * 128];  // 40960 B
    _Float16* H = SMEM;             // h window, updated in place per layer
    _Float16* G = SMEM + WR * 128;  // gated
    const int n = blockIdx.y, tb = blockIdx.x, t0 = tb * TT;
    const int tid = threadIdx.x;
    const int wave = __builtin_amdgcn_readfirstlane(tid >> 6);  // 0..7
    const int lane = tid & 63, q = lane >> 4, ml = lane & 15;

    // ---- skip accumulator (persistent f32 across the NL layers)
    floatx4 sacc[2][4];
    if (FIRST) {
        #pragma unroll
        for (int mt = 0; mt < 2; ++mt)
            #pragma unroll
            for (int r = 0; r < 4; ++r) {
                float bias = ssum[32 * wave + mt * 16 + q * 4 + r];
                #pragma unroll
                for (int nt = 0; nt < 4; ++nt) sacc[mt][nt][r] = bias;
            }
    } else {
        const _Float16* cp = chunk + ((size_t)n * NTB + tb) * 16384;
        #pragma unroll
        for (int mt = 0; mt < 2; ++mt)
            #pragma unroll
            for (int nt = 0; nt < 4; ++nt) {
                size_t o = (size_t)((((wave * 2 + mt) * 4) + nt) * 64 + lane) * 4;
                half4 v = *(const half4*)&cp[o];
                #pragma unroll
                for (int r = 0; r < 4; ++r) sacc[mt][nt][r] = (float)v[r];
            }
    }

    // ---- stage WR-row window (t0-HALO .. t0+63); t<0 rows = 0 (causal pad)
    const _Float16* hn = h_in + (size_t)n * WLEN * 128;
    #pragma unroll
    for (int it = 0; it < (WR * 16 + 511) / 512; ++it) {
        int idx = it * 512 + tid;
        if (idx < WR * 16) {
            int seg = idx & 15;          // 16B segment (8 f16)
            int w = idx >> 4;            // window row
            int src_t = t0 - HALO + w;
            half8 v = (half8)(_Float16)0.0f;
            if (src_t >= 0)
                v = *(const half8*)&hn[(size_t)src_t * 128 + seg * 8];
            *(half8*)&H[SX(w, seg * 8)] = v;
        }
    }
    __syncthreads();

    const _Float16* cw  = cw0;
    const float*    cb  = cb0;
    const _Float16* rsw = rsw0;
    const float*    rb  = rb0;
    const _Float16* skw = skw0;

    #pragma clang loop unroll(disable)
    for (int j = 0; j < NL; ++j) {
        const int d = 1 << (E0 + j);

        // ---- conv GEMM + GLU over NT row-tiles in passes of <=4
        #pragma unroll
        for (int base = 0; base < NT; base += 4) {
            floatx4 acc[2][4];
            #pragma unroll
            for (int mt = 0; mt < 2; ++mt)
                #pragma unroll
                for (int r = 0; r < 4; ++r) {
                    float bias = cb[32 * wave + mt * 16 + q * 4 + r];
                    #pragma unroll
                    for (int nt = 0; nt < 4; ++nt) acc[mt][nt][r] = bias;
                }
            #pragma unroll
            for (int hp = 0; hp < 2; ++hp) {
                for (int ks = 0; ks < 4; ++ks) {
                    half8 a[2];
                    #pragma unroll
                    for (int mt = 0; mt < 2; ++mt)
                        a[mt] = *(const half8*)&cw[((((2 * wave + mt) * 8) + hp * 4 + ks) * 64 + lane) * 8];
                    #pragma unroll
                    for (int nt = 0; nt < 4; ++nt) {
                        if (base + nt < NT) {
                            int row = (base + nt) * 16 + ml;
                            if (!hp) { row -= d; if (row < 0) row = 0; }  // tap0 = t-d, clamped
                            half8 b = *(const half8*)&H[SX(row, ks * 32 + q * 8)];
                            #pragma unroll
                            for (int mt = 0; mt < 2; ++mt)
                                acc[mt][nt] = __builtin_amdgcn_mfma_f32_16x16x32_f16(a[mt], b, acc[mt][nt], 0, 0, 0);
                        }
                    }
                }
            }
            // GLU -> G (separate buffer from H: no barrier needed before write)
            #pragma unroll
            for (int mt = 0; mt < 2; ++mt)
                #pragma unroll
                for (int nt = 0; nt < 4; ++nt) {
                    if (base + nt < NT) {
                        float g0 = acc[mt][nt][0] * sigmoidf_(acc[mt][nt][1]);
                        float g1 = acc[mt][nt][2] * sigmoidf_(acc[mt][nt][3]);
                        _Float16 p[2] = {(_Float16)g0, (_Float16)g1};
                        *(uint32_t*)&G[SX((base + nt) * 16 + ml, 16 * wave + mt * 8 + 2 * q)] = *(uint32_t*)p;
                    }
                }
        }
        __syncthreads();  // G complete before skip/res read it

        // ---- skip GEMM over the valid tile (window rows HALO..HALO+63) -> sacc
        #pragma unroll
        for (int ks = 0; ks < 4; ++ks) {
            half8 a[2];
            #pragma unroll
            for (int mt = 0; mt < 2; ++mt)
                a[mt] = *(const half8*)&skw[((((2 * wave + mt) * 4) + ks) * 64 + lane) * 8];
            #pragma unroll
            for (int nt = 0; nt < 4; ++nt) {
                half8 b = *(const half8*)&G[SX(HALO + nt * 16 + ml, ks * 32 + q * 8)];
                #pragma unroll
                for (int mt = 0; mt < 2; ++mt)
                    sacc[mt][nt] = __builtin_amdgcn_mfma_f32_16x16x32_f16(a[mt], b, sacc[mt][nt], 0, 0, 0);
            }
        }

        // ---- res GEMM + in-place H update (wave owns 16-channel column block)
        #pragma unroll
        for (int base = 0; base < NT; base += 4) {
            floatx4 racc[4];
            #pragma unroll
            for (int r = 0; r < 4; ++r) {
                float bias = rb[16 * wave + q * 4 + r];
                #pragma unroll
                for (int nt = 0; nt < 4; ++nt) racc[nt][r] = bias;
            }
            #pragma unroll
            for (int ks = 0; ks < 4; ++ks) {
                half8 a = *(const half8*)&rsw[(((wave * 4) + ks) * 64 + lane) * 8];
                #pragma unroll
                for (int nt = 0; nt < 4; ++nt) {
                    if (base + nt < NT) {
                        half8 b = *(const half8*)&G[SX((base + nt) * 16 + ml, ks * 32 + q * 8)];
                        racc[nt] = __builtin_amdgcn_mfma_f32_16x16x32_f16(a, b, racc[nt], 0, 0, 0);
                    }
                }
            }
            #pragma unroll
            for (int nt = 0; nt < 4; ++nt) {
                if (base + nt < NT) {
                    int w = (base + nt) * 16 + ml;
                    int c = 16 * wave + q * 4;
                    half4 hv = *(const half4*)&H[SX(w, c)];
                    half4 o;
                    #pragma unroll
                    for (int r = 0; r < 4; ++r)
                        o[r] = (_Float16)(racc[nt][r] + (float)hv[r]);
                    *(half4*)&H[SX(w, c)] = o;
                }
            }
        }
        __syncthreads();  // H updated before next layer's conv reads

        cw  += 65536; cb += 256; rsw += 16384; rb += 128; skw += 32768;
    }

    // ---- store h_out: window rows HALO..HALO+63 -> t0..t0+63
    _Float16* ho = h_out + (size_t)n * WLEN * 128;
    #pragma unroll
    for (int it = 0; it < 2; ++it) {
        int idx = it * 512 + tid;        // 0..1023
        int seg = idx & 15;
        int w64 = idx >> 4;              // 0..63
        *(half8*)&ho[(size_t)(t0 + w64) * 128 + seg * 8] =
            *(const half8*)&H[SX(HALO + w64, seg * 8)];
    }

    // ---- store skip accumulator (f16 frag-linear, same layout as singles/head)
    {
        _Float16* cp = chunk + ((size_t)n * NTB + tb) * 16384;
        #pragma unroll
        for (int mt = 0; mt < 2; ++mt)
            #pragma unroll
            for (int nt = 0; nt < 4; ++nt) {
                size_t o = (size_t)((((wave * 2 + mt) * 4) + nt) * 64 + lane) * 4;
                half4 v;
                #pragma unroll
                for (int r = 0; r < 4; ++r) v[r] = (_Float16)sacc[mt][nt][r];
                *(half4*)&cp[o] = v;
            }
    }
}

// ---------------- single residual layer (d>=16), 8 waves ----------------
// Chunk-RMW read hoisted to kernel entry (latency hidden under stage+conv);
// LAST=true drops the dead res GEMM + h store (l=29 only).
template <bool LAST>
__global__ __launch_bounds__(512, 8) void layer_kernel(
    const _Float16* __restrict__ h_in, _Float16* __restrict__ h_out,
    _Float16* __restrict__ chunk,
    const _Float16* __restrict__ cw, const float* __restrict__ cb,
    const _Float16* __restrict__ rsw, const float* __restrict__ rb,
    const _Float16* __restrict__ skw, int d) {
    __shared__ _Float16 SMEM[2 * TT * GROW];  // 34816 B -> 4 blocks/CU
    _Float16* X0 = SMEM;
    _Float16* X1 = SMEM + TT * GROW;
    _Float16* G  = X0;  // alias: tap0 dead after conv reads
    const int n = blockIdx.y, tb = blockIdx.x, t0 = tb * TT;
    const int tid = threadIdx.x;
    const int wave = __builtin_amdgcn_readfirstlane(tid >> 6);  // 0..7
    const int lane = tid & 63, q = lane >> 4, ml = lane & 15;

    // ---- hoisted chunk-RMW read (independent of everything; hides under conv)
    _Float16* cp = chunk + ((size_t)n * NTB + tb) * 16384;
    half4 cold[2][4];
    #pragma unroll
    for (int mt = 0; mt < 2; ++mt)
        #pragma unroll
        for (int nt = 0; nt < 4; ++nt) {
            size_t o = (size_t)((((wave * 2 + mt) * 4) + nt) * 64 + lane) * 4;
            cold[mt][nt] = *(const half4*)&cp[o];
        }

    const _Float16* hn = h_in + (size_t)n * WLEN * 128;
    #pragma unroll
    for (int it = 0; it < 4; ++it) {
        int idx = it * 512 + tid;
        int seg = idx & 15;
        int rowc = (idx >> 4) & 63;
        int tap = idx >> 10;
        int src_t = t0 + rowc - (tap ? 0 : d);
        half8 v = (half8)(_Float16)0.0f;
        if (src_t >= 0)
            v = *(const half8*)&hn[(size_t)src_t * 128 + seg * 8];
        _Float16* Xb = tap ? X1 : X0;
        *(half8*)&Xb[rowc * GROW + seg * 8] = v;
    }
    __syncthreads();

    floatx4 acc[2][4];
    #pragma unroll
    for (int mt = 0; mt < 2; ++mt)
        #pragma unroll
        for (int r = 0; r < 4; ++r) {
            float bias = cb[32 * wave + mt * 16 + q * 4 + r];
            #pragma unroll
            for (int nt = 0; nt < 4; ++nt) acc[mt][nt][r] = bias;
        }
    #pragma unroll
    for (int hp = 0; hp < 2; ++hp) {
        const _Float16* Xb = hp ? X1 : X0;
        for (int ks = 0; ks < 4; ++ks) {
            half8 a[2];
            #pragma unroll
            for (int mt = 0; mt < 2; ++mt)
                a[mt] = *(const half8*)&cw[((((2 * wave + mt) * 8) + hp * 4 + ks) * 64 + lane) * 8];
            #pragma unroll
            for (int nt = 0; nt < 4; ++nt) {
                half8 b = *(const half8*)&Xb[(nt * 16 + ml) * GROW + ks * 32 + q * 8];
                #pragma unroll
                for (int mt = 0; mt < 2; ++mt)
                    acc[mt][nt] = __builtin_amdgcn_mfma_f32_16x16x32_f16(a[mt], b, acc[mt][nt], 0, 0, 0);
            }
        }
    }
    __syncthreads();

    #pragma unroll
    for (int mt = 0; mt < 2; ++mt)
        #pragma unroll
        for (int nt = 0; nt < 4; ++nt) {
            float g0 = acc[mt][nt][0] * sigmoidf_(acc[mt][nt][1]);
            float g1 = acc[mt][nt][2] * sigmoidf_(acc[mt][nt][3]);
            _Float16 p[2] = {(_Float16)g0, (_Float16)g1};
            *(uint32_t*)&G[(nt * 16 + ml) * GROW + 16 * wave + mt * 8 + 2 * q] = *(uint32_t*)p;
        }
    __syncthreads();

    {
        floatx4 sacc[2][4];
        #pragma unroll
        for (int mt = 0; mt < 2; ++mt)
            #pragma unroll
            for (int nt = 0; nt < 4; ++nt)
                #pragma unroll
                for (int r = 0; r < 4; ++r) sacc[mt][nt][r] = 0.0f;
        #pragma unroll
        for (int ks = 0; ks < 4; ++ks) {
            half8 a[2];
            #pragma unroll
            for (int mt = 0; mt < 2; ++mt)
                a[mt] = *(const half8*)&skw[((((2 * wave + mt) * 4) + ks) * 64 + lane) * 8];
            #pragma unroll
            for (int nt = 0; nt < 4; ++nt) {
                half8 b = *(const half8*)&G[(nt * 16 + ml) * GROW + ks * 32 + q * 8];
                #pragma unroll
                for (int mt = 0; mt < 2; ++mt)
                    sacc[mt][nt] = __builtin_amdgcn_mfma_f32_16x16x32_f16(a[mt], b, sacc[mt][nt], 0, 0, 0);
            }
        }
        #pragma unroll
        for (int mt = 0; mt < 2; ++mt)
            #pragma unroll
            for (int nt = 0; nt < 4; ++nt) {
                size_t o = (size_t)((((wave * 2 + mt) * 4) + nt) * 64 + lane) * 4;
                half4 w;
                #pragma unroll
                for (int r = 0; r < 4; ++r)
                    w[r] = (_Float16)(sacc[mt][nt][r] + (float)cold[mt][nt][r]);
                *(half4*)&cp[o] = w;
            }
    }

    if (!LAST) {
        floatx4 racc[4];
        #pragma unroll
        for (int r = 0; r < 4; ++r) {
            float bias = rb[16 * wave + q * 4 + r];
            #pragma unroll
            for (int nt = 0; nt < 4; ++nt) racc[nt][r] = bias;
        }
        #pragma unroll
        for (int ks = 0; ks < 4; ++ks) {
            half8 a = *(const half8*)&rsw[(((wave * 4) + ks) * 64 + lane) * 8];
            #pragma unroll
            for (int nt = 0; nt < 4; ++nt) {
                half8 b = *(const half8*)&G[(nt * 16 + ml) * GROW + ks * 32 + q * 8];
                racc[nt] = __builtin_amdgcn_mfma_f32_16x16x32_f16(a, b, racc[nt], 0, 0, 0);
            }
        }
        _Float16* ho = h_out + (size_t)n * WLEN * 128;
        #pragma unroll
        for (int nt = 0; nt < 4; ++nt) {
            int tt = nt * 16 + ml;
            int c = 16 * wave + q * 4;
            half4 hv = *(const half4*)&X1[tt * GROW + c];  // tap1 = h_in(c,t)
            half4 o;
            #pragma unroll
            for (int r = 0; r < 4; ++r)
                o[r] = (_Float16)(racc[nt][r] + (float)hv[r]);
            *(half4*)&ho[(size_t)(t0 + tt) * 128 + c] = o;
        }
    }
}

// ---------------- head (round-7, 8 waves) ----------------
__global__ __launch_bounds__(512, 8) void head_kernel(
    float* __restrict__ out, const _Float16* __restrict__ chunk,
    const _Float16* __restrict__ aw, const float* __restrict__ ab,
    const _Float16* __restrict__ bw, const float* __restrict__ bb) {
    __shared__ _Float16 X[TT * XROW];
    const int n = blockIdx.y, tb = blockIdx.x, t0 = tb * TT;
    const int tid = threadIdx.x;
    const int wave = __builtin_amdgcn_readfirstlane(tid >> 6);
    const int lane = tid & 63, q = lane >> 4, ml = lane & 15;

    {
        const _Float16* cp = chunk + ((size_t)n * NTB + tb) * 16384;
        #pragma unroll
        for (int mt = 0; mt < 2; ++mt)
            #pragma unroll
            for (int nt = 0; nt < 4; ++nt) {
                size_t o = (size_t)((((wave * 2 + mt) * 4) + nt) * 64 + lane) * 4;
                half4 v = *(const half4*)&cp[o];
                half4 z;
                #pragma unroll
                for (int r = 0; r < 4; ++r)
                    z[r] = (_Float16)fmaxf((float)v[r], 0.0f);
                *(half4*)&X[(nt * 16 + ml) * XROW + 32 * wave + mt * 16 + q * 4] = z;
            }
    }
    __syncthreads();

    floatx4 acc[2][4];
    #pragma unroll
    for (int mt = 0; mt < 2; ++mt)
        #pragma unroll
        for (int r = 0; r < 4; ++r) {
            float bias = ab[32 * wave + mt * 16 + q * 4 + r];
            #pragma unroll
            for (int nt = 0; nt < 4; ++nt) acc[mt][nt][r] = bias;
        }
    for (int ks = 0; ks < 8; ++ks) {
        half8 a[2];
        #pragma unroll
        for (int mt = 0; mt < 2; ++mt)
            a[mt] = *(const half8*)&aw[((((2 * wave + mt) * 8) + ks) * 64 + lane) * 8];
        #pragma unroll
        for (int nt = 0; nt < 4; ++nt) {
            half8 b = *(const half8*)&X[(nt * 16 + ml) * XROW + ks * 32 + q * 8];
            #pragma unroll
            for (int mt = 0; mt < 2; ++mt)
                acc[mt][nt] = __builtin_amdgcn_mfma_f32_16x16x32_f16(a[mt], b, acc[mt][nt], 0, 0, 0);
        }
    }
    __syncthreads();
    #pragma unroll
    for (int mt = 0; mt < 2; ++mt)
        #pragma unroll
        for (int nt = 0; nt < 4; ++nt) {
            half4 z;
            #pragma unroll
            for (int r = 0; r < 4; ++r)
                z[r] = (_Float16)fmaxf(acc[mt][nt][r], 0.0f);
            *(half4*)&X[(nt * 16 + ml) * XROW + 32 * wave + mt * 16 + q * 4] = z;
        }
    __syncthreads();

    #pragma unroll
    for (int mt = 0; mt < 2; ++mt)
        #pragma unroll
        for (int r = 0; r < 4; ++r) {
            float bias = bb[32 * wave + mt * 16 + q * 4 + r];
            #pragma unroll
            for (int nt = 0; nt < 4; ++nt) acc[mt][nt][r] = bias;
        }
    for (int ks = 0; ks < 8; ++ks) {
        half8 a[2];
        #pragma unroll
        for (int mt = 0; mt < 2; ++mt)
            a[mt] = *(const half8*)&bw[((((2 * wave + mt) * 8) + ks) * 64 + lane) * 8];
        #pragma unroll
        for (int nt = 0; nt < 4; ++nt) {
            half8 b = *(const half8*)&X[(nt * 16 + ml) * XROW + ks * 32 + q * 8];
            #pragma unroll
            for (int mt = 0; mt < 2; ++mt)
                acc[mt][nt] = __builtin_amdgcn_mfma_f32_16x16x32_f16(a[mt], b, acc[mt][nt], 0, 0, 0);
        }
    }
    float* on = out + (size_t)n * S * WLEN;
    #pragma unroll
    for (int mt = 0; mt < 2; ++mt)
        #pragma unroll
        for (int nt = 0; nt < 4; ++nt)
            #pragma unroll
            for (int r = 0; r < 4; ++r) {
                int o = 32 * wave + mt * 16 + q * 4 + r;
                int tt = t0 + nt * 16 + ml;
                on[(size_t)o * WLEN + tt] = acc[mt][nt][r];
            }
}

extern "C" void kernel_launch(void* const* d_in, const int* in_sizes, int n_in,
                              void* d_out, int out_size, void* d_ws, size_t ws_size,
                              hipStream_t stream) {
    (void)in_sizes; (void)n_in; (void)out_size; (void)ws_size;
    const float* x       = (const float*)d_in[0];
    const float* w_shift = (const float*)d_in[1];
    const float* b_shift = (const float*)d_in[2];
    const float* conv_w  = (const float*)d_in[3];
    const float* conv_b  = (const float*)d_in[4];
    const float* res_w   = (const float*)d_in[5];
    const float* res_b   = (const float*)d_in[6];
    const float* skip_w  = (const float*)d_in[7];
    const float* skip_b  = (const float*)d_in[8];
    const float* a_w     = (const float*)d_in[9];
    const float* a_b     = (const float*)d_in[10];
    const float* b_w     = (const float*)d_in[11];
    const float* b_b     = (const float*)d_in[12];
    float* out = (float*)d_out;

    char* ws = (char*)d_ws;
    size_t off = 0;
    _Float16* hA    = (_Float16*)(ws + off); off += (size_t)NB * WLEN * 128 * 2;
    _Float16* hB    = (_Float16*)(ws + off); off += (size_t)NB * WLEN * 128 * 2;
    _Float16* chunk = (_Float16*)(ws + off); off += (size_t)NB * NTB * 16384 * 2;
    _Float16* cw  = (_Float16*)(ws + off); off += (size_t)NLAYERS * 256 * 256 * 2;
    _Float16* rsw = (_Float16*)(ws + off); off += (size_t)NLAYERS * 128 * 128 * 2;
    _Float16* skw = (_Float16*)(ws + off); off += (size_t)NLAYERS * 256 * 128 * 2;
    _Float16* aw  = (_Float16*)(ws + off); off += 256 * 256 * 2;
    _Float16* bw  = (_Float16*)(ws + off); off += 256 * 256 * 2;
    float* cbp  = (float*)(ws + off); off += (size_t)NLAYERS * 256 * 4;
    float* ssum = (float*)(ws + off); off += 256 * 4;
    // total ~74.3 MB

    prep_kernel<<<512, 256, 0, stream>>>(conv_w, res_w, skip_w, a_w, b_w,
                                         conv_b, skip_b,
                                         cw, rsw, skw, aw, bw, cbp, ssum);
    front_kernel<<<dim3(WLEN / 256, NB), 256, 0, stream>>>(x, w_shift, b_shift, hA);

    const dim3 grid(NTB, NB);
    _Float16* hin = hA;
    _Float16* hout = hB;
    for (int s = 0; s < 3; ++s) {
        const int l0 = s * 10;
        // stackA: layers l0..l0+3 (d=1,2,4,8), 80-row window
        if (s == 0)
            stack_kernel<0, 4, 5, 16, true><<<grid, 512, 0, stream>>>(
                hin, hout, chunk,
                cw + (size_t)l0 * 65536, cbp + l0 * 256,
                rsw + (size_t)l0 * 16384, res_b + l0 * 128,
                skw + (size_t)l0 * 32768, ssum);
        else
            stack_kernel<0, 4, 5, 16, false><<<grid, 512, 0, stream>>>(
                hin, hout, chunk,
                cw + (size_t)l0 * 65536, cbp + l0 * 256,
                rsw + (size_t)l0 * 16384, res_b + l0 * 128,
                skw + (size_t)l0 * 32768, ssum);
        { _Float16* tmp = hin; hin = hout; hout = tmp; }
        // single layers l0+4 .. l0+9 (d = 16..512)
        for (int jj = 4; jj < 10; ++jj) {
            const int l = l0 + jj;
            const int dil = 1 << jj;
            if (l == NLAYERS - 1)
                layer_kernel<true><<<grid, 512, 0, stream>>>(
                    hin, hout, chunk,
                    cw + (size_t)l * 65536, cbp + l * 256,
                    rsw + (size_t)l * 16384, res_b + l * 128,
                    skw + (size_t)l * 32768, dil);
            else
                layer_kernel<false><<<grid, 512, 0, stream>>>(
                    hin, hout, chunk,
                    cw + (size_t)l * 65536, cbp + l * 256,
                    rsw + (size_t)l * 16384, res_b + l * 128,
                    skw + (size_t)l * 32768, dil);
            _Float16* tmp = hin; hin = hout; hout = tmp;
        }
    }

    head_kernel<<<grid, 512, 0, stream>>>(out, chunk, aw, a_b, bw, b_b);
}

// Round 16
// 1061.456 us; speedup vs baseline: 1.2351x; 1.2351x over previous
//
#include <hip/hip_runtime.h>
#include <math.h>

// WaveNet forward, round 14: revert the hoist, keep the dead-code cut.
// - Round-13 postmortem: hoisting the chunk-RMW read regressed singles
//   33 -> ~47 us (+257 us total). Same failure mode as rounds 9/10: 16 extra
//   VGPRs live across two barriers under launch_bounds(512,8)'s 64-VGPR cap
//   -> spill/sched pressure. At 32 waves/CU the RMW load latency was already
//   hidden by TLP; the hoist bought nothing and cost registers.
// - This round: singles reverted to round-12 code EXACTLY (VGPR 32, 33 us,
//   verified); keep only template<LAST> (l=29 skips dead res GEMM + h store;
//   LAST=false instantiation is byte-identical to round-12).
// - stackA (d=1,2,4,8 fused, waves_per_eu(2,4)) and head verbatim.
// - Coop/grid.sync stays deleted (5x regression, round 4).
//
// MFMA 16x16x32_f16: A lane: A[m=lane&15][k=(lane>>4)*8+j]; D lane:
// D[row=(lane>>4)*4+reg][col=lane&15]. Conv A-rows interleaved (a0,b0,a1,b1..)
// so GLU happens in registers. Conv K order: k = tap*128 + c.

#define NB 4
#define WLEN 16384
#define C 128
#define S 256
#define NLAYERS 30
#define TT 64
#define NTB (WLEN / TT)   // 256 tiles per sample
#define XROW 264          // head X row stride (f16): 256 + 8 pad
#define GROW 136          // single-layer tile row stride (f16): 128 + 8 pad

// swizzled f16 index into a pad-free 128-col row (stack kernel only)
#define SX(row, c) ((row) * 128 + ((c) ^ (((row) & 7) << 3)))

typedef _Float16 half8 __attribute__((ext_vector_type(8)));
typedef _Float16 half4 __attribute__((ext_vector_type(4)));
typedef float floatx4 __attribute__((ext_vector_type(4)));

__device__ __forceinline__ float sigmoidf_(float v) {
    return 1.0f / (1.0f + __expf(-v));
}

// ---------------- weight packing (unchanged layouts) ----------------
__global__ void prep_kernel(const float* __restrict__ conv_w,
                            const float* __restrict__ res_w,
                            const float* __restrict__ skip_w,
                            const float* __restrict__ a_w,
                            const float* __restrict__ b_w,
                            const float* __restrict__ conv_b,
                            const float* __restrict__ skip_b,
                            _Float16* __restrict__ cw,
                            _Float16* __restrict__ rsw,
                            _Float16* __restrict__ skw,
                            _Float16* __restrict__ aw,
                            _Float16* __restrict__ bw,
                            float* __restrict__ cbp,
                            float* __restrict__ ssum) {
    const int ncw = NLAYERS * 256 * 256;
    const int nrs = NLAYERS * 128 * 128;
    const int nsk = NLAYERS * 256 * 128;
    const int nab = 256 * 256;
    const int ncb = NLAYERS * 256;
    const int total = ncw + nrs + nsk + nab + nab + ncb + 256;
    for (int idx = blockIdx.x * blockDim.x + threadIdx.x; idx < total;
         idx += gridDim.x * blockDim.x) {
        int i = idx;
        if (i < ncw) {
            int j = i & 7, lane = (i >> 3) & 63, rest = i >> 9;
            int ks = rest & 7; rest >>= 3;
            int mt = rest & 15; int l = rest >> 4;
            int mp = mt * 16 + (lane & 15);
            int orow = (mp >> 1) + (mp & 1) * 128;
            int k = ks * 32 + (lane >> 4) * 8 + j;
            int tap = k >> 7, c = k & 127;
            cw[i] = (_Float16)conv_w[(((size_t)l * 256 + orow) * 128 + c) * 2 + tap];
        } else if (i < ncw + nrs) {
            i -= ncw;
            int j = i & 7, lane = (i >> 3) & 63, rest = i >> 9;
            int ks = rest & 3; rest >>= 2;
            int mt = rest & 7; int l = rest >> 3;
            int m = mt * 16 + (lane & 15);
            int k = ks * 32 + (lane >> 4) * 8 + j;
            rsw[i] = (_Float16)res_w[((size_t)l * 128 + m) * 128 + k];
        } else if (i < ncw + nrs + nsk) {
            i -= ncw + nrs;
            int j = i & 7, lane = (i >> 3) & 63, rest = i >> 9;
            int ks = rest & 3; rest >>= 2;
            int mt = rest & 15; int l = rest >> 4;
            int m = mt * 16 + (lane & 15);
            int k = ks * 32 + (lane >> 4) * 8 + j;
            skw[i] = (_Float16)skip_w[((size_t)l * 256 + m) * 128 + k];
        } else if (i < ncw + nrs + nsk + nab) {
            i -= ncw + nrs + nsk;
            int j = i & 7, lane = (i >> 3) & 63, rest = i >> 9;
            int ks = rest & 7; int mt = rest >> 3;
            aw[i] = (_Float16)a_w[(mt * 16 + (lane & 15)) * 256 + ks * 32 + (lane >> 4) * 8 + j];
        } else if (i < ncw + nrs + nsk + 2 * nab) {
            i -= ncw + nrs + nsk + nab;
            int j = i & 7, lane = (i >> 3) & 63, rest = i >> 9;
            int ks = rest & 7; int mt = rest >> 3;
            bw[i] = (_Float16)b_w[(mt * 16 + (lane & 15)) * 256 + ks * 32 + (lane >> 4) * 8 + j];
        } else if (i < ncw + nrs + nsk + 2 * nab + ncb) {
            i -= ncw + nrs + nsk + 2 * nab;
            int mp = i & 255; int l = i >> 8;
            cbp[i] = conv_b[l * 256 + (mp >> 1) + (mp & 1) * 128];
        } else {
            i -= ncw + nrs + nsk + 2 * nab + ncb;
            float s = 0.f;
            for (int l = 0; l < NLAYERS; ++l) s += skip_b[l * 256 + i];
            ssum[i] = s;
        }
    }
}

// ---------------- front: h0 (f16, [n][t][c]) ----------------
__global__ void front_kernel(const float* __restrict__ x,
                             const float* __restrict__ w_shift,
                             const float* __restrict__ b_shift,
                             _Float16* __restrict__ h) {
    const int n = blockIdx.y;
    const int t = blockIdx.x * 256 + threadIdx.x;
    float x1 = (t >= 1) ? x[n * WLEN + t - 1] : 0.0f;
    float x2 = (t >= 2) ? x[n * WLEN + t - 2] : 0.0f;
    _Float16* hq = h + ((size_t)n * WLEN + t) * 128;
    #pragma unroll
    for (int c0 = 0; c0 < 128; c0 += 8) {
        half8 v;
        #pragma unroll
        for (int j = 0; j < 8; ++j) {
            int c = c0 + j;
            v[j] = (_Float16)fmaf(w_shift[2 * c], x2,
                                  fmaf(w_shift[2 * c + 1], x1, b_shift[c]));
        }
        *(half8*)&hq[c0] = v;
    }
}

// ---------------- fused stack kernel (d=1,2,4,8 only) ----------------
// Window rows w=0..79 map to t = t0-16+w. Valid rows 16..79 = t0..t0+63.
// All 5 row-tiles computed uniformly; tap0 row clamped to >=0. LDS pad-free
// + XOR swizzle (SX). amdgpu_waves_per_eu(2,4): firm 128-VGPR budget, no
// spill (round-11/12 verified: VGPR 112, FETCH 35.7MB, WRITE 49MB, 128 us).
template <int E0, int NL, int NT, int HALO, bool FIRST>
__global__ __launch_bounds__(512)
__attribute__((amdgpu_waves_per_eu(2, 4))) void stack_kernel(
    const _Float16* __restrict__ h_in, _Float16* __restrict__ h_out,
    _Float16* __restrict__ chunk,
    const _Float16* __restrict__ cw0, const float* __restrict__ cb0,
    const _Float16* __restrict__ rsw0, const float* __restrict__ rb0,
    const _Float16* __restrict__ skw0, const float* __restrict__ ssum) {
    constexpr int WR = NT * 16;
    __shared__ _Float16 SMEM[2 * WR * 128];  // 40960 B
    _Float16* H = SMEM;             // h window, updated in place per layer
    _Float16* G = SMEM + WR * 128;  // gated
    const int n = blockIdx.y, tb = blockIdx.x, t0 = tb * TT;
    const int tid = threadIdx.x;
    const int wave = __builtin_amdgcn_readfirstlane(tid >> 6);  // 0..7
    const int lane = tid & 63, q = lane >> 4, ml = lane & 15;

    // ---- skip accumulator (persistent f32 across the NL layers)
    floatx4 sacc[2][4];
    if (FIRST) {
        #pragma unroll
        for (int mt = 0; mt < 2; ++mt)
            #pragma unroll
            for (int r = 0; r < 4; ++r) {
                float bias = ssum[32 * wave + mt * 16 + q * 4 + r];
                #pragma unroll
                for (int nt = 0; nt < 4; ++nt) sacc[mt][nt][r] = bias;
            }
    } else {
        const _Float16* cp = chunk + ((size_t)n * NTB + tb) * 16384;
        #pragma unroll
        for (int mt = 0; mt < 2; ++mt)
            #pragma unroll
            for (int nt = 0; nt < 4; ++nt) {
                size_t o = (size_t)((((wave * 2 + mt) * 4) + nt) * 64 + lane) * 4;
                half4 v = *(const half4*)&cp[o];
                #pragma unroll
                for (int r = 0; r < 4; ++r) sacc[mt][nt][r] = (float)v[r];
            }
    }

    // ---- stage WR-row window (t0-HALO .. t0+63); t<0 rows = 0 (causal pad)
    const _Float16* hn = h_in + (size_t)n * WLEN * 128;
    #pragma unroll
    for (int it = 0; it < (WR * 16 + 511) / 512; ++it) {
        int idx = it * 512 + tid;
        if (idx < WR * 16) {
            int seg = idx & 15;          // 16B segment (8 f16)
            int w = idx >> 4;            // window row
            int src_t = t0 - HALO + w;
            half8 v = (half8)(_Float16)0.0f;
            if (src_t >= 0)
                v = *(const half8*)&hn[(size_t)src_t * 128 + seg * 8];
            *(half8*)&H[SX(w, seg * 8)] = v;
        }
    }
    __syncthreads();

    const _Float16* cw  = cw0;
    const float*    cb  = cb0;
    const _Float16* rsw = rsw0;
    const float*    rb  = rb0;
    const _Float16* skw = skw0;

    #pragma clang loop unroll(disable)
    for (int j = 0; j < NL; ++j) {
        const int d = 1 << (E0 + j);

        // ---- conv GEMM + GLU over NT row-tiles in passes of <=4
        #pragma unroll
        for (int base = 0; base < NT; base += 4) {
            floatx4 acc[2][4];
            #pragma unroll
            for (int mt = 0; mt < 2; ++mt)
                #pragma unroll
                for (int r = 0; r < 4; ++r) {
                    float bias = cb[32 * wave + mt * 16 + q * 4 + r];
                    #pragma unroll
                    for (int nt = 0; nt < 4; ++nt) acc[mt][nt][r] = bias;
                }
            #pragma unroll
            for (int hp = 0; hp < 2; ++hp) {
                for (int ks = 0; ks < 4; ++ks) {
                    half8 a[2];
                    #pragma unroll
                    for (int mt = 0; mt < 2; ++mt)
                        a[mt] = *(const half8*)&cw[((((2 * wave + mt) * 8) + hp * 4 + ks) * 64 + lane) * 8];
                    #pragma unroll
                    for (int nt = 0; nt < 4; ++nt) {
                        if (base + nt < NT) {
                            int row = (base + nt) * 16 + ml;
                            if (!hp) { row -= d; if (row < 0) row = 0; }  // tap0 = t-d, clamped
                            half8 b = *(const half8*)&H[SX(row, ks * 32 + q * 8)];
                            #pragma unroll
                            for (int mt = 0; mt < 2; ++mt)
                                acc[mt][nt] = __builtin_amdgcn_mfma_f32_16x16x32_f16(a[mt], b, acc[mt][nt], 0, 0, 0);
                        }
                    }
                }
            }
            // GLU -> G (separate buffer from H: no barrier needed before write)
            #pragma unroll
            for (int mt = 0; mt < 2; ++mt)
                #pragma unroll
                for (int nt = 0; nt < 4; ++nt) {
                    if (base + nt < NT) {
                        float g0 = acc[mt][nt][0] * sigmoidf_(acc[mt][nt][1]);
                        float g1 = acc[mt][nt][2] * sigmoidf_(acc[mt][nt][3]);
                        _Float16 p[2] = {(_Float16)g0, (_Float16)g1};
                        *(uint32_t*)&G[SX((base + nt) * 16 + ml, 16 * wave + mt * 8 + 2 * q)] = *(uint32_t*)p;
                    }
                }
        }
        __syncthreads();  // G complete before skip/res read it

        // ---- skip GEMM over the valid tile (window rows HALO..HALO+63) -> sacc
        #pragma unroll
        for (int ks = 0; ks < 4; ++ks) {
            half8 a[2];
            #pragma unroll
            for (int mt = 0; mt < 2; ++mt)
                a[mt] = *(const half8*)&skw[((((2 * wave + mt) * 4) + ks) * 64 + lane) * 8];
            #pragma unroll
            for (int nt = 0; nt < 4; ++nt) {
                half8 b = *(const half8*)&G[SX(HALO + nt * 16 + ml, ks * 32 + q * 8)];
                #pragma unroll
                for (int mt = 0; mt < 2; ++mt)
                    sacc[mt][nt] = __builtin_amdgcn_mfma_f32_16x16x32_f16(a[mt], b, sacc[mt][nt], 0, 0, 0);
            }
        }

        // ---- res GEMM + in-place H update (wave owns 16-channel column block)
        #pragma unroll
        for (int base = 0; base < NT; base += 4) {
            floatx4 racc[4];
            #pragma unroll
            for (int r = 0; r < 4; ++r) {
                float bias = rb[16 * wave + q * 4 + r];
                #pragma unroll
                for (int nt = 0; nt < 4; ++nt) racc[nt][r] = bias;
            }
            #pragma unroll
            for (int ks = 0; ks < 4; ++ks) {
                half8 a = *(const half8*)&rsw[(((wave * 4) + ks) * 64 + lane) * 8];
                #pragma unroll
                for (int nt = 0; nt < 4; ++nt) {
                    if (base + nt < NT) {
                        half8 b = *(const half8*)&G[SX((base + nt) * 16 + ml, ks * 32 + q * 8)];
                        racc[nt] = __builtin_amdgcn_mfma_f32_16x16x32_f16(a, b, racc[nt], 0, 0, 0);
                    }
                }
            }
            #pragma unroll
            for (int nt = 0; nt < 4; ++nt) {
                if (base + nt < NT) {
                    int w = (base + nt) * 16 + ml;
                    int c = 16 * wave + q * 4;
                    half4 hv = *(const half4*)&H[SX(w, c)];
                    half4 o;
                    #pragma unroll
                    for (int r = 0; r < 4; ++r)
                        o[r] = (_Float16)(racc[nt][r] + (float)hv[r]);
                    *(half4*)&H[SX(w, c)] = o;
                }
            }
        }
        __syncthreads();  // H updated before next layer's conv reads

        cw  += 65536; cb += 256; rsw += 16384; rb += 128; skw += 32768;
    }

    // ---- store h_out: window rows HALO..HALO+63 -> t0..t0+63
    _Float16* ho = h_out + (size_t)n * WLEN * 128;
    #pragma unroll
    for (int it = 0; it < 2; ++it) {
        int idx = it * 512 + tid;        // 0..1023
        int seg = idx & 15;
        int w64 = idx >> 4;              // 0..63
        *(half8*)&ho[(size_t)(t0 + w64) * 128 + seg * 8] =
            *(const half8*)&H[SX(HALO + w64, seg * 8)];
    }

    // ---- store skip accumulator (f16 frag-linear, same layout as singles/head)
    {
        _Float16* cp = chunk + ((size_t)n * NTB + tb) * 16384;
        #pragma unroll
        for (int mt = 0; mt < 2; ++mt)
            #pragma unroll
            for (int nt = 0; nt < 4; ++nt) {
                size_t o = (size_t)((((wave * 2 + mt) * 4) + nt) * 64 + lane) * 4;
                half4 v;
                #pragma unroll
                for (int r = 0; r < 4; ++r) v[r] = (_Float16)sacc[mt][nt][r];
                *(half4*)&cp[o] = v;
            }
    }
}

// ---------------- single residual layer (d>=16), 8 waves (round-12 code) ----------------
// LAST=true only drops the dead res GEMM + h store (l=29); LAST=false is
// byte-identical to the verified round-12 kernel (VGPR 32, ~33 us).
template <bool LAST>
__global__ __launch_bounds__(512, 8) void layer_kernel(
    const _Float16* __restrict__ h_in, _Float16* __restrict__ h_out,
    _Float16* __restrict__ chunk,
    const _Float16* __restrict__ cw, const float* __restrict__ cb,
    const _Float16* __restrict__ rsw, const float* __restrict__ rb,
    const _Float16* __restrict__ skw, int d) {
    __shared__ _Float16 SMEM[2 * TT * GROW];  // 34816 B -> 4 blocks/CU
    _Float16* X0 = SMEM;
    _Float16* X1 = SMEM + TT * GROW;
    _Float16* G  = X0;  // alias: tap0 dead after conv reads
    const int n = blockIdx.y, tb = blockIdx.x, t0 = tb * TT;
    const int tid = threadIdx.x;
    const int wave = __builtin_amdgcn_readfirstlane(tid >> 6);  // 0..7
    const int lane = tid & 63, q = lane >> 4, ml = lane & 15;

    const _Float16* hn = h_in + (size_t)n * WLEN * 128;
    #pragma unroll
    for (int it = 0; it < 4; ++it) {
        int idx = it * 512 + tid;
        int seg = idx & 15;
        int rowc = (idx >> 4) & 63;
        int tap = idx >> 10;
        int src_t = t0 + rowc - (tap ? 0 : d);
        half8 v = (half8)(_Float16)0.0f;
        if (src_t >= 0)
            v = *(const half8*)&hn[(size_t)src_t * 128 + seg * 8];
        _Float16* Xb = tap ? X1 : X0;
        *(half8*)&Xb[rowc * GROW + seg * 8] = v;
    }
    __syncthreads();

    floatx4 acc[2][4];
    #pragma unroll
    for (int mt = 0; mt < 2; ++mt)
        #pragma unroll
        for (int r = 0; r < 4; ++r) {
            float bias = cb[32 * wave + mt * 16 + q * 4 + r];
            #pragma unroll
            for (int nt = 0; nt < 4; ++nt) acc[mt][nt][r] = bias;
        }
    #pragma unroll
    for (int hp = 0; hp < 2; ++hp) {
        const _Float16* Xb = hp ? X1 : X0;
        for (int ks = 0; ks < 4; ++ks) {
            half8 a[2];
            #pragma unroll
            for (int mt = 0; mt < 2; ++mt)
                a[mt] = *(const half8*)&cw[((((2 * wave + mt) * 8) + hp * 4 + ks) * 64 + lane) * 8];
            #pragma unroll
            for (int nt = 0; nt < 4; ++nt) {
                half8 b = *(const half8*)&Xb[(nt * 16 + ml) * GROW + ks * 32 + q * 8];
                #pragma unroll
                for (int mt = 0; mt < 2; ++mt)
                    acc[mt][nt] = __builtin_amdgcn_mfma_f32_16x16x32_f16(a[mt], b, acc[mt][nt], 0, 0, 0);
            }
        }
    }
    __syncthreads();

    #pragma unroll
    for (int mt = 0; mt < 2; ++mt)
        #pragma unroll
        for (int nt = 0; nt < 4; ++nt) {
            float g0 = acc[mt][nt][0] * sigmoidf_(acc[mt][nt][1]);
            float g1 = acc[mt][nt][2] * sigmoidf_(acc[mt][nt][3]);
            _Float16 p[2] = {(_Float16)g0, (_Float16)g1};
            *(uint32_t*)&G[(nt * 16 + ml) * GROW + 16 * wave + mt * 8 + 2 * q] = *(uint32_t*)p;
        }
    __syncthreads();

    {
        floatx4 sacc[2][4];
        #pragma unroll
        for (int mt = 0; mt < 2; ++mt)
            #pragma unroll
            for (int nt = 0; nt < 4; ++nt)
                #pragma unroll
                for (int r = 0; r < 4; ++r) sacc[mt][nt][r] = 0.0f;
        #pragma unroll
        for (int ks = 0; ks < 4; ++ks) {
            half8 a[2];
            #pragma unroll
            for (int mt = 0; mt < 2; ++mt)
                a[mt] = *(const half8*)&skw[((((2 * wave + mt) * 4) + ks) * 64 + lane) * 8];
            #pragma unroll
            for (int nt = 0; nt < 4; ++nt) {
                half8 b = *(const half8*)&G[(nt * 16 + ml) * GROW + ks * 32 + q * 8];
                #pragma unroll
                for (int mt = 0; mt < 2; ++mt)
                    sacc[mt][nt] = __builtin_amdgcn_mfma_f32_16x16x32_f16(a[mt], b, sacc[mt][nt], 0, 0, 0);
            }
        }
        _Float16* cp = chunk + ((size_t)n * NTB + tb) * 16384;
        #pragma unroll
        for (int mt = 0; mt < 2; ++mt)
            #pragma unroll
            for (int nt = 0; nt < 4; ++nt) {
                size_t o = (size_t)((((wave * 2 + mt) * 4) + nt) * 64 + lane) * 4;
                half4 v = *(const half4*)&cp[o];
                half4 w;
                #pragma unroll
                for (int r = 0; r < 4; ++r)
                    w[r] = (_Float16)(sacc[mt][nt][r] + (float)v[r]);
                *(half4*)&cp[o] = w;
            }
    }

    if (!LAST) {
        floatx4 racc[4];
        #pragma unroll
        for (int r = 0; r < 4; ++r) {
            float bias = rb[16 * wave + q * 4 + r];
            #pragma unroll
            for (int nt = 0; nt < 4; ++nt) racc[nt][r] = bias;
        }
        #pragma unroll
        for (int ks = 0; ks < 4; ++ks) {
            half8 a = *(const half8*)&rsw[(((wave * 4) + ks) * 64 + lane) * 8];
            #pragma unroll
            for (int nt = 0; nt < 4; ++nt) {
                half8 b = *(const half8*)&G[(nt * 16 + ml) * GROW + ks * 32 + q * 8];
                racc[nt] = __builtin_amdgcn_mfma_f32_16x16x32_f16(a, b, racc[nt], 0, 0, 0);
            }
        }
        _Float16* ho = h_out + (size_t)n * WLEN * 128;
        #pragma unroll
        for (int nt = 0; nt < 4; ++nt) {
            int tt = nt * 16 + ml;
            int c = 16 * wave + q * 4;
            half4 hv = *(const half4*)&X1[tt * GROW + c];  // tap1 = h_in(c,t)
            half4 o;
            #pragma unroll
            for (int r = 0; r < 4; ++r)
                o[r] = (_Float16)(racc[nt][r] + (float)hv[r]);
            *(half4*)&ho[(size_t)(t0 + tt) * 128 + c] = o;
        }
    }
}

// ---------------- head (round-7, 8 waves) ----------------
__global__ __launch_bounds__(512, 8) void head_kernel(
    float* __restrict__ out, const _Float16* __restrict__ chunk,
    const _Float16* __restrict__ aw, const float* __restrict__ ab,
    const _Float16* __restrict__ bw, const float* __restrict__ bb) {
    __shared__ _Float16 X[TT * XROW];
    const int n = blockIdx.y, tb = blockIdx.x, t0 = tb * TT;
    const int tid = threadIdx.x;
    const int wave = __builtin_amdgcn_readfirstlane(tid >> 6);
    const int lane = tid & 63, q = lane >> 4, ml = lane & 15;

    {
        const _Float16* cp = chunk + ((size_t)n * NTB + tb) * 16384;
        #pragma unroll
        for (int mt = 0; mt < 2; ++mt)
            #pragma unroll
            for (int nt = 0; nt < 4; ++nt) {
                size_t o = (size_t)((((wave * 2 + mt) * 4) + nt) * 64 + lane) * 4;
                half4 v = *(const half4*)&cp[o];
                half4 z;
                #pragma unroll
                for (int r = 0; r < 4; ++r)
                    z[r] = (_Float16)fmaxf((float)v[r], 0.0f);
                *(half4*)&X[(nt * 16 + ml) * XROW + 32 * wave + mt * 16 + q * 4] = z;
            }
    }
    __syncthreads();

    floatx4 acc[2][4];
    #pragma unroll
    for (int mt = 0; mt < 2; ++mt)
        #pragma unroll
        for (int r = 0; r < 4; ++r) {
            float bias = ab[32 * wave + mt * 16 + q * 4 + r];
            #pragma unroll
            for (int nt = 0; nt < 4; ++nt) acc[mt][nt][r] = bias;
        }
    for (int ks = 0; ks < 8; ++ks) {
        half8 a[2];
        #pragma unroll
        for (int mt = 0; mt < 2; ++mt)
            a[mt] = *(const half8*)&aw[((((2 * wave + mt) * 8) + ks) * 64 + lane) * 8];
        #pragma unroll
        for (int nt = 0; nt < 4; ++nt) {
            half8 b = *(const half8*)&X[(nt * 16 + ml) * XROW + ks * 32 + q * 8];
            #pragma unroll
            for (int mt = 0; mt < 2; ++mt)
                acc[mt][nt] = __builtin_amdgcn_mfma_f32_16x16x32_f16(a[mt], b, acc[mt][nt], 0, 0, 0);
        }
    }
    __syncthreads();
    #pragma unroll
    for (int mt = 0; mt < 2; ++mt)
        #pragma unroll
        for (int nt = 0; nt < 4; ++nt) {
            half4 z;
            #pragma unroll
            for (int r = 0; r < 4; ++r)
                z[r] = (_Float16)fmaxf(acc[mt][nt][r], 0.0f);
            *(half4*)&X[(nt * 16 + ml) * XROW + 32 * wave + mt * 16 + q * 4] = z;
        }
    __syncthreads();

    #pragma unroll
    for (int mt = 0; mt < 2; ++mt)
        #pragma unroll
        for (int r = 0; r < 4; ++r) {
            float bias = bb[32 * wave + mt * 16 + q * 4 + r];
            #pragma unroll
            for (int nt = 0; nt < 4; ++nt) acc[mt][nt][r] = bias;
        }
    for (int ks = 0; ks < 8; ++ks) {
        half8 a[2];
        #pragma unroll
        for (int mt = 0; mt < 2; ++mt)
            a[mt] = *(const half8*)&bw[((((2 * wave + mt) * 8) + ks) * 64 + lane) * 8];
        #pragma unroll
        for (int nt = 0; nt < 4; ++nt) {
            half8 b = *(const half8*)&X[(nt * 16 + ml) * XROW + ks * 32 + q * 8];
            #pragma unroll
            for (int mt = 0; mt < 2; ++mt)
                acc[mt][nt] = __builtin_amdgcn_mfma_f32_16x16x32_f16(a[mt], b, acc[mt][nt], 0, 0, 0);
        }
    }
    float* on = out + (size_t)n * S * WLEN;
    #pragma unroll
    for (int mt = 0; mt < 2; ++mt)
        #pragma unroll
        for (int nt = 0; nt < 4; ++nt)
            #pragma unroll
            for (int r = 0; r < 4; ++r) {
                int o = 32 * wave + mt * 16 + q * 4 + r;
                int tt = t0 + nt * 16 + ml;
                on[(size_t)o * WLEN + tt] = acc[mt][nt][r];
            }
}

extern "C" void kernel_launch(void* const* d_in, const int* in_sizes, int n_in,
                              void* d_out, int out_size, void* d_ws, size_t ws_size,
                              hipStream_t stream) {
    (void)in_sizes; (void)n_in; (void)out_size; (void)ws_size;
    const float* x       = (const float*)d_in[0];
    const float* w_shift = (const float*)d_in[1];
    const float* b_shift = (const float*)d_in[2];
    const float* conv_w  = (const float*)d_in[3];
    const float* conv_b  = (const float*)d_in[4];
    const float* res_w   = (const float*)d_in[5];
    const float* res_b   = (const float*)d_in[6];
    const float* skip_w  = (const float*)d_in[7];
    const float* skip_b  = (const float*)d_in[8];
    const float* a_w     = (const float*)d_in[9];
    const float* a_b     = (const float*)d_in[10];
    const float* b_w     = (const float*)d_in[11];
    const float* b_b     = (const float*)d_in[12];
    float* out = (float*)d_out;

    char* ws = (char*)d_ws;
    size_t off = 0;
    _Float16* hA    = (_Float16*)(ws + off); off += (size_t)NB * WLEN * 128 * 2;
    _Float16* hB    = (_Float16*)(ws + off); off += (size_t)NB * WLEN * 128 * 2;
    _Float16* chunk = (_Float16*)(ws + off); off += (size_t)NB * NTB * 16384 * 2;
    _Float16* cw  = (_Float16*)(ws + off); off += (size_t)NLAYERS * 256 * 256 * 2;
    _Float16* rsw = (_Float16*)(ws + off); off += (size_t)NLAYERS * 128 * 128 * 2;
    _Float16* skw = (_Float16*)(ws + off); off += (size_t)NLAYERS * 256 * 128 * 2;
    _Float16* aw  = (_Float16*)(ws + off); off += 256 * 256 * 2;
    _Float16* bw  = (_Float16*)(ws + off); off += 256 * 256 * 2;
    float* cbp  = (float*)(ws + off); off += (size_t)NLAYERS * 256 * 4;
    float* ssum = (float*)(ws + off); off += 256 * 4;
    // total ~74.3 MB

    prep_kernel<<<512, 256, 0, stream>>>(conv_w, res_w, skip_w, a_w, b_w,
                                         conv_b, skip_b,
                                         cw, rsw, skw, aw, bw, cbp, ssum);
    front_kernel<<<dim3(WLEN / 256, NB), 256, 0, stream>>>(x, w_shift, b_shift, hA);

    const dim3 grid(NTB, NB);
    _Float16* hin = hA;
    _Float16* hout = hB;
    for (int s = 0; s < 3; ++s) {
        const int l0 = s * 10;
        // stackA: layers l0..l0+3 (d=1,2,4,8), 80-row window
        if (s == 0)
            stack_kernel<0, 4, 5, 16, true><<<grid, 512, 0, stream>>>(
                hin, hout, chunk,
                cw + (size_t)l0 * 65536, cbp + l0 * 256,
                rsw + (size_t)l0 * 16384, res_b + l0 * 128,
                skw + (size_t)l0 * 32768, ssum);
        else
            stack_kernel<0, 4, 5, 16, false><<<grid, 512, 0, stream>>>(
                hin, hout, chunk,
                cw + (size_t)l0 * 65536, cbp + l0 * 256,
                rsw + (size_t)l0 * 16384, res_b + l0 * 128,
                skw + (size_t)l0 * 32768, ssum);
        { _Float16* tmp = hin; hin = hout; hout = tmp; }
        // single layers l0+4 .. l0+9 (d = 16..512)
        for (int jj = 4; jj < 10; ++jj) {
            const int l = l0 + jj;
            const int dil = 1 << jj;
            if (l == NLAYERS - 1)
                layer_kernel<true><<<grid, 512, 0, stream>>>(
                    hin, hout, chunk,
                    cw + (size_t)l * 65536, cbp + l * 256,
                    rsw + (size_t)l * 16384, res_b + l * 128,
                    skw + (size_t)l * 32768, dil);
            else
                layer_kernel<false><<<grid, 512, 0, stream>>>(
                    hin, hout, chunk,
                    cw + (size_t)l * 65536, cbp + l * 256,
                    rsw + (size_t)l * 16384, res_b + l * 128,
                    skw + (size_t)l * 32768, dil);
            _Float16* tmp = hin; hin = hout; hout = tmp;
        }
    }

    head_kernel<<<grid, 512, 0, stream>>>(out, chunk, aw, a_b, bw, b_b);
}

// Round 17
// 1026.107 us; speedup vs baseline: 1.2776x; 1.0345x over previous
//
#include <hip/hip_runtime.h>
#include <math.h>

// WaveNet forward, round 15: fuse head into the last layer.
// - Round-14 postmortem: LAST dead-code cut was noise-level (1061 vs 1053).
//   Structure is plateaued; remaining levers must delete work/dispatches.
// - Change: last_head_kernel = layer l=29 (conv+GLU+skip) + head fused.
//   l=29's final skip sum (sacc + chunk cold) goes relu -> head X LDS
//   directly (numerics identical: relu and f16-round commute for >=0),
//   then a_w/b_w GEMMs + logits store. Deletes: chunk write (33.5 MB),
//   head's chunk read (33.5 MB), head staging, one dispatch.
//   SMEM union fits (33792 <= 34816 B, still 4 blocks/CU); phases strictly
//   sequential -> no cross-barrier live state (round-13 trap avoided).
// - Singles (17x, round-12 code verbatim), stackA, front, prep unchanged.
// - Coop/grid.sync stays deleted (5x regression, round 4).
//
// MFMA 16x16x32_f16: A lane: A[m=lane&15][k=(lane>>4)*8+j]; D lane:
// D[row=(lane>>4)*4+reg][col=lane&15]. Conv A-rows interleaved (a0,b0,a1,b1..)
// so GLU happens in registers. Conv K order: k = tap*128 + c.

#define NB 4
#define WLEN 16384
#define C 128
#define S 256
#define NLAYERS 30
#define TT 64
#define NTB (WLEN / TT)   // 256 tiles per sample
#define XROW 264          // head X row stride (f16): 256 + 8 pad
#define GROW 136          // single-layer tile row stride (f16): 128 + 8 pad

// swizzled f16 index into a pad-free 128-col row (stack kernel only)
#define SX(row, c) ((row) * 128 + ((c) ^ (((row) & 7) << 3)))

typedef _Float16 half8 __attribute__((ext_vector_type(8)));
typedef _Float16 half4 __attribute__((ext_vector_type(4)));
typedef float floatx4 __attribute__((ext_vector_type(4)));

__device__ __forceinline__ float sigmoidf_(float v) {
    return 1.0f / (1.0f + __expf(-v));
}

// ---------------- weight packing (unchanged layouts) ----------------
__global__ void prep_kernel(const float* __restrict__ conv_w,
                            const float* __restrict__ res_w,
                            const float* __restrict__ skip_w,
                            const float* __restrict__ a_w,
                            const float* __restrict__ b_w,
                            const float* __restrict__ conv_b,
                            const float* __restrict__ skip_b,
                            _Float16* __restrict__ cw,
                            _Float16* __restrict__ rsw,
                            _Float16* __restrict__ skw,
                            _Float16* __restrict__ aw,
                            _Float16* __restrict__ bw,
                            float* __restrict__ cbp,
                            float* __restrict__ ssum) {
    const int ncw = NLAYERS * 256 * 256;
    const int nrs = NLAYERS * 128 * 128;
    const int nsk = NLAYERS * 256 * 128;
    const int nab = 256 * 256;
    const int ncb = NLAYERS * 256;
    const int total = ncw + nrs + nsk + nab + nab + ncb + 256;
    for (int idx = blockIdx.x * blockDim.x + threadIdx.x; idx < total;
         idx += gridDim.x * blockDim.x) {
        int i = idx;
        if (i < ncw) {
            int j = i & 7, lane = (i >> 3) & 63, rest = i >> 9;
            int ks = rest & 7; rest >>= 3;
            int mt = rest & 15; int l = rest >> 4;
            int mp = mt * 16 + (lane & 15);
            int orow = (mp >> 1) + (mp & 1) * 128;
            int k = ks * 32 + (lane >> 4) * 8 + j;
            int tap = k >> 7, c = k & 127;
            cw[i] = (_Float16)conv_w[(((size_t)l * 256 + orow) * 128 + c) * 2 + tap];
        } else if (i < ncw + nrs) {
            i -= ncw;
            int j = i & 7, lane = (i >> 3) & 63, rest = i >> 9;
            int ks = rest & 3; rest >>= 2;
            int mt = rest & 7; int l = rest >> 3;
            int m = mt * 16 + (lane & 15);
            int k = ks * 32 + (lane >> 4) * 8 + j;
            rsw[i] = (_Float16)res_w[((size_t)l * 128 + m) * 128 + k];
        } else if (i < ncw + nrs + nsk) {
            i -= ncw + nrs;
            int j = i & 7, lane = (i >> 3) & 63, rest = i >> 9;
            int ks = rest & 3; rest >>= 2;
            int mt = rest & 15; int l = rest >> 4;
            int m = mt * 16 + (lane & 15);
            int k = ks * 32 + (lane >> 4) * 8 + j;
            skw[i] = (_Float16)skip_w[((size_t)l * 256 + m) * 128 + k];
        } else if (i < ncw + nrs + nsk + nab) {
            i -= ncw + nrs + nsk;
            int j = i & 7, lane = (i >> 3) & 63, rest = i >> 9;
            int ks = rest & 7; int mt = rest >> 3;
            aw[i] = (_Float16)a_w[(mt * 16 + (lane & 15)) * 256 + ks * 32 + (lane >> 4) * 8 + j];
        } else if (i < ncw + nrs + nsk + 2 * nab) {
            i -= ncw + nrs + nsk + nab;
            int j = i & 7, lane = (i >> 3) & 63, rest = i >> 9;
            int ks = rest & 7; int mt = rest >> 3;
            bw[i] = (_Float16)b_w[(mt * 16 + (lane & 15)) * 256 + ks * 32 + (lane >> 4) * 8 + j];
        } else if (i < ncw + nrs + nsk + 2 * nab + ncb) {
            i -= ncw + nrs + nsk + 2 * nab;
            int mp = i & 255; int l = i >> 8;
            cbp[i] = conv_b[l * 256 + (mp >> 1) + (mp & 1) * 128];
        } else {
            i -= ncw + nrs + nsk + 2 * nab + ncb;
            float s = 0.f;
            for (int l = 0; l < NLAYERS; ++l) s += skip_b[l * 256 + i];
            ssum[i] = s;
        }
    }
}

// ---------------- front: h0 (f16, [n][t][c]) ----------------
__global__ void front_kernel(const float* __restrict__ x,
                             const float* __restrict__ w_shift,
                             const float* __restrict__ b_shift,
                             _Float16* __restrict__ h) {
    const int n = blockIdx.y;
    const int t = blockIdx.x * 256 + threadIdx.x;
    float x1 = (t >= 1) ? x[n * WLEN + t - 1] : 0.0f;
    float x2 = (t >= 2) ? x[n * WLEN + t - 2] : 0.0f;
    _Float16* hq = h + ((size_t)n * WLEN + t) * 128;
    #pragma unroll
    for (int c0 = 0; c0 < 128; c0 += 8) {
        half8 v;
        #pragma unroll
        for (int j = 0; j < 8; ++j) {
            int c = c0 + j;
            v[j] = (_Float16)fmaf(w_shift[2 * c], x2,
                                  fmaf(w_shift[2 * c + 1], x1, b_shift[c]));
        }
        *(half8*)&hq[c0] = v;
    }
}

// ---------------- fused stack kernel (d=1,2,4,8 only) ----------------
// Window rows w=0..79 map to t = t0-16+w. Valid rows 16..79 = t0..t0+63.
// All 5 row-tiles computed uniformly; tap0 row clamped to >=0. LDS pad-free
// + XOR swizzle (SX). amdgpu_waves_per_eu(2,4): firm 128-VGPR budget, no
// spill (round-11/12 verified: VGPR 112, FETCH 35.7MB, WRITE 49MB, 128 us).
template <int E0, int NL, int NT, int HALO, bool FIRST>
__global__ __launch_bounds__(512)
__attribute__((amdgpu_waves_per_eu(2, 4))) void stack_kernel(
    const _Float16* __restrict__ h_in, _Float16* __restrict__ h_out,
    _Float16* __restrict__ chunk,
    const _Float16* __restrict__ cw0, const float* __restrict__ cb0,
    const _Float16* __restrict__ rsw0, const float* __restrict__ rb0,
    const _Float16* __restrict__ skw0, const float* __restrict__ ssum) {
    constexpr int WR = NT * 16;
    __shared__ _Float16 SMEM[2 * WR * 128];  // 40960 B
    _Float16* H = SMEM;             // h window, updated in place per layer
    _Float16* G = SMEM + WR * 128;  // gated
    const int n = blockIdx.y, tb = blockIdx.x, t0 = tb * TT;
    const int tid = threadIdx.x;
    const int wave = __builtin_amdgcn_readfirstlane(tid >> 6);  // 0..7
    const int lane = tid & 63, q = lane >> 4, ml = lane & 15;

    // ---- skip accumulator (persistent f32 across the NL layers)
    floatx4 sacc[2][4];
    if (FIRST) {
        #pragma unroll
        for (int mt = 0; mt < 2; ++mt)
            #pragma unroll
            for (int r = 0; r < 4; ++r) {
                float bias = ssum[32 * wave + mt * 16 + q * 4 + r];
                #pragma unroll
                for (int nt = 0; nt < 4; ++nt) sacc[mt][nt][r] = bias;
            }
    } else {
        const _Float16* cp = chunk + ((size_t)n * NTB + tb) * 16384;
        #pragma unroll
        for (int mt = 0; mt < 2; ++mt)
            #pragma unroll
            for (int nt = 0; nt < 4; ++nt) {
                size_t o = (size_t)((((wave * 2 + mt) * 4) + nt) * 64 + lane) * 4;
                half4 v = *(const half4*)&cp[o];
                #pragma unroll
                for (int r = 0; r < 4; ++r) sacc[mt][nt][r] = (float)v[r];
            }
    }

    // ---- stage WR-row window (t0-HALO .. t0+63); t<0 rows = 0 (causal pad)
    const _Float16* hn = h_in + (size_t)n * WLEN * 128;
    #pragma unroll
    for (int it = 0; it < (WR * 16 + 511) / 512; ++it) {
        int idx = it * 512 + tid;
        if (idx < WR * 16) {
            int seg = idx & 15;          // 16B segment (8 f16)
            int w = idx >> 4;            // window row
            int src_t = t0 - HALO + w;
            half8 v = (half8)(_Float16)0.0f;
            if (src_t >= 0)
                v = *(const half8*)&hn[(size_t)src_t * 128 + seg * 8];
            *(half8*)&H[SX(w, seg * 8)] = v;
        }
    }
    __syncthreads();

    const _Float16* cw  = cw0;
    const float*    cb  = cb0;
    const _Float16* rsw = rsw0;
    const float*    rb  = rb0;
    const _Float16* skw = skw0;

    #pragma clang loop unroll(disable)
    for (int j = 0; j < NL; ++j) {
        const int d = 1 << (E0 + j);

        // ---- conv GEMM + GLU over NT row-tiles in passes of <=4
        #pragma unroll
        for (int base = 0; base < NT; base += 4) {
            floatx4 acc[2][4];
            #pragma unroll
            for (int mt = 0; mt < 2; ++mt)
                #pragma unroll
                for (int r = 0; r < 4; ++r) {
                    float bias = cb[32 * wave + mt * 16 + q * 4 + r];
                    #pragma unroll
                    for (int nt = 0; nt < 4; ++nt) acc[mt][nt][r] = bias;
                }
            #pragma unroll
            for (int hp = 0; hp < 2; ++hp) {
                for (int ks = 0; ks < 4; ++ks) {
                    half8 a[2];
                    #pragma unroll
                    for (int mt = 0; mt < 2; ++mt)
                        a[mt] = *(const half8*)&cw[((((2 * wave + mt) * 8) + hp * 4 + ks) * 64 + lane) * 8];
                    #pragma unroll
                    for (int nt = 0; nt < 4; ++nt) {
                        if (base + nt < NT) {
                            int row = (base + nt) * 16 + ml;
                            if (!hp) { row -= d; if (row < 0) row = 0; }  // tap0 = t-d, clamped
                            half8 b = *(const half8*)&H[SX(row, ks * 32 + q * 8)];
                            #pragma unroll
                            for (int mt = 0; mt < 2; ++mt)
                                acc[mt][nt] = __builtin_amdgcn_mfma_f32_16x16x32_f16(a[mt], b, acc[mt][nt], 0, 0, 0);
                        }
                    }
                }
            }
            // GLU -> G (separate buffer from H: no barrier needed before write)
            #pragma unroll
            for (int mt = 0; mt < 2; ++mt)
                #pragma unroll
                for (int nt = 0; nt < 4; ++nt) {
                    if (base + nt < NT) {
                        float g0 = acc[mt][nt][0] * sigmoidf_(acc[mt][nt][1]);
                        float g1 = acc[mt][nt][2] * sigmoidf_(acc[mt][nt][3]);
                        _Float16 p[2] = {(_Float16)g0, (_Float16)g1};
                        *(uint32_t*)&G[SX((base + nt) * 16 + ml, 16 * wave + mt * 8 + 2 * q)] = *(uint32_t*)p;
                    }
                }
        }
        __syncthreads();  // G complete before skip/res read it

        // ---- skip GEMM over the valid tile (window rows HALO..HALO+63) -> sacc
        #pragma unroll
        for (int ks = 0; ks < 4; ++ks) {
            half8 a[2];
            #pragma unroll
            for (int mt = 0; mt < 2; ++mt)
                a[mt] = *(const half8*)&skw[((((2 * wave + mt) * 4) + ks) * 64 + lane) * 8];
            #pragma unroll
            for (int nt = 0; nt < 4; ++nt) {
                half8 b = *(const half8*)&G[SX(HALO + nt * 16 + ml, ks * 32 + q * 8)];
                #pragma unroll
                for (int mt = 0; mt < 2; ++mt)
                    sacc[mt][nt] = __builtin_amdgcn_mfma_f32_16x16x32_f16(a[mt], b, sacc[mt][nt], 0, 0, 0);
            }
        }

        // ---- res GEMM + in-place H update (wave owns 16-channel column block)
        #pragma unroll
        for (int base = 0; base < NT; base += 4) {
            floatx4 racc[4];
            #pragma unroll
            for (int r = 0; r < 4; ++r) {
                float bias = rb[16 * wave + q * 4 + r];
                #pragma unroll
                for (int nt = 0; nt < 4; ++nt) racc[nt][r] = bias;
            }
            #pragma unroll
            for (int ks = 0; ks < 4; ++ks) {
                half8 a = *(const half8*)&rsw[(((wave * 4) + ks) * 64 + lane) * 8];
                #pragma unroll
                for (int nt = 0; nt < 4; ++nt) {
                    if (base + nt < NT) {
                        half8 b = *(const half8*)&G[SX((base + nt) * 16 + ml, ks * 32 + q * 8)];
                        racc[nt] = __builtin_amdgcn_mfma_f32_16x16x32_f16(a, b, racc[nt], 0, 0, 0);
                    }
                }
            }
            #pragma unroll
            for (int nt = 0; nt < 4; ++nt) {
                if (base + nt < NT) {
                    int w = (base + nt) * 16 + ml;
                    int c = 16 * wave + q * 4;
                    half4 hv = *(const half4*)&H[SX(w, c)];
                    half4 o;
                    #pragma unroll
                    for (int r = 0; r < 4; ++r)
                        o[r] = (_Float16)(racc[nt][r] + (float)hv[r]);
                    *(half4*)&H[SX(w, c)] = o;
                }
            }
        }
        __syncthreads();  // H updated before next layer's conv reads

        cw  += 65536; cb += 256; rsw += 16384; rb += 128; skw += 32768;
    }

    // ---- store h_out: window rows HALO..HALO+63 -> t0..t0+63
    _Float16* ho = h_out + (size_t)n * WLEN * 128;
    #pragma unroll
    for (int it = 0; it < 2; ++it) {
        int idx = it * 512 + tid;        // 0..1023
        int seg = idx & 15;
        int w64 = idx >> 4;              // 0..63
        *(half8*)&ho[(size_t)(t0 + w64) * 128 + seg * 8] =
            *(const half8*)&H[SX(HALO + w64, seg * 8)];
    }

    // ---- store skip accumulator (f16 frag-linear, same layout as singles/head)
    {
        _Float16* cp = chunk + ((size_t)n * NTB + tb) * 16384;
        #pragma unroll
        for (int mt = 0; mt < 2; ++mt)
            #pragma unroll
            for (int nt = 0; nt < 4; ++nt) {
                size_t o = (size_t)((((wave * 2 + mt) * 4) + nt) * 64 + lane) * 4;
                half4 v;
                #pragma unroll
                for (int r = 0; r < 4; ++r) v[r] = (_Float16)sacc[mt][nt][r];
                *(half4*)&cp[o] = v;
            }
    }
}

// ---------------- single residual layer (d>=16), 8 waves (round-12 code) ----------------
__global__ __launch_bounds__(512, 8) void layer_kernel(
    const _Float16* __restrict__ h_in, _Float16* __restrict__ h_out,
    _Float16* __restrict__ chunk,
    const _Float16* __restrict__ cw, const float* __restrict__ cb,
    const _Float16* __restrict__ rsw, const float* __restrict__ rb,
    const _Float16* __restrict__ skw, int d) {
    __shared__ _Float16 SMEM[2 * TT * GROW];  // 34816 B -> 4 blocks/CU
    _Float16* X0 = SMEM;
    _Float16* X1 = SMEM + TT * GROW;
    _Float16* G  = X0;  // alias: tap0 dead after conv reads
    const int n = blockIdx.y, tb = blockIdx.x, t0 = tb * TT;
    const int tid = threadIdx.x;
    const int wave = __builtin_amdgcn_readfirstlane(tid >> 6);  // 0..7
    const int lane = tid & 63, q = lane >> 4, ml = lane & 15;

    const _Float16* hn = h_in + (size_t)n * WLEN * 128;
    #pragma unroll
    for (int it = 0; it < 4; ++it) {
        int idx = it * 512 + tid;
        int seg = idx & 15;
        int rowc = (idx >> 4) & 63;
        int tap = idx >> 10;
        int src_t = t0 + rowc - (tap ? 0 : d);
        half8 v = (half8)(_Float16)0.0f;
        if (src_t >= 0)
            v = *(const half8*)&hn[(size_t)src_t * 128 + seg * 8];
        _Float16* Xb = tap ? X1 : X0;
        *(half8*)&Xb[rowc * GROW + seg * 8] = v;
    }
    __syncthreads();

    floatx4 acc[2][4];
    #pragma unroll
    for (int mt = 0; mt < 2; ++mt)
        #pragma unroll
        for (int r = 0; r < 4; ++r) {
            float bias = cb[32 * wave + mt * 16 + q * 4 + r];
            #pragma unroll
            for (int nt = 0; nt < 4; ++nt) acc[mt][nt][r] = bias;
        }
    #pragma unroll
    for (int hp = 0; hp < 2; ++hp) {
        const _Float16* Xb = hp ? X1 : X0;
        for (int ks = 0; ks < 4; ++ks) {
            half8 a[2];
            #pragma unroll
            for (int mt = 0; mt < 2; ++mt)
                a[mt] = *(const half8*)&cw[((((2 * wave + mt) * 8) + hp * 4 + ks) * 64 + lane) * 8];
            #pragma unroll
            for (int nt = 0; nt < 4; ++nt) {
                half8 b = *(const half8*)&Xb[(nt * 16 + ml) * GROW + ks * 32 + q * 8];
                #pragma unroll
                for (int mt = 0; mt < 2; ++mt)
                    acc[mt][nt] = __builtin_amdgcn_mfma_f32_16x16x32_f16(a[mt], b, acc[mt][nt], 0, 0, 0);
            }
        }
    }
    __syncthreads();

    #pragma unroll
    for (int mt = 0; mt < 2; ++mt)
        #pragma unroll
        for (int nt = 0; nt < 4; ++nt) {
            float g0 = acc[mt][nt][0] * sigmoidf_(acc[mt][nt][1]);
            float g1 = acc[mt][nt][2] * sigmoidf_(acc[mt][nt][3]);
            _Float16 p[2] = {(_Float16)g0, (_Float16)g1};
            *(uint32_t*)&G[(nt * 16 + ml) * GROW + 16 * wave + mt * 8 + 2 * q] = *(uint32_t*)p;
        }
    __syncthreads();

    {
        floatx4 sacc[2][4];
        #pragma unroll
        for (int mt = 0; mt < 2; ++mt)
            #pragma unroll
            for (int nt = 0; nt < 4; ++nt)
                #pragma unroll
                for (int r = 0; r < 4; ++r) sacc[mt][nt][r] = 0.0f;
        #pragma unroll
        for (int ks = 0; ks < 4; ++ks) {
            half8 a[2];
            #pragma unroll
            for (int mt = 0; mt < 2; ++mt)
                a[mt] = *(const half8*)&skw[((((2 * wave + mt) * 4) + ks) * 64 + lane) * 8];
            #pragma unroll
            for (int nt = 0; nt < 4; ++nt) {
                half8 b = *(const half8*)&G[(nt * 16 + ml) * GROW + ks * 32 + q * 8];
                #pragma unroll
                for (int mt = 0; mt < 2; ++mt)
                    sacc[mt][nt] = __builtin_amdgcn_mfma_f32_16x16x32_f16(a[mt], b, sacc[mt][nt], 0, 0, 0);
            }
        }
        _Float16* cp = chunk + ((size_t)n * NTB + tb) * 16384;
        #pragma unroll
        for (int mt = 0; mt < 2; ++mt)
            #pragma unroll
            for (int nt = 0; nt < 4; ++nt) {
                size_t o = (size_t)((((wave * 2 + mt) * 4) + nt) * 64 + lane) * 4;
                half4 v = *(const half4*)&cp[o];
                half4 w;
                #pragma unroll
                for (int r = 0; r < 4; ++r)
                    w[r] = (_Float16)(sacc[mt][nt][r] + (float)v[r]);
                *(half4*)&cp[o] = w;
            }
    }

    {
        floatx4 racc[4];
        #pragma unroll
        for (int r = 0; r < 4; ++r) {
            float bias = rb[16 * wave + q * 4 + r];
            #pragma unroll
            for (int nt = 0; nt < 4; ++nt) racc[nt][r] = bias;
        }
        #pragma unroll
        for (int ks = 0; ks < 4; ++ks) {
            half8 a = *(const half8*)&rsw[(((wave * 4) + ks) * 64 + lane) * 8];
            #pragma unroll
            for (int nt = 0; nt < 4; ++nt) {
                half8 b = *(const half8*)&G[(nt * 16 + ml) * GROW + ks * 32 + q * 8];
                racc[nt] = __builtin_amdgcn_mfma_f32_16x16x32_f16(a, b, racc[nt], 0, 0, 0);
            }
        }
        _Float16* ho = h_out + (size_t)n * WLEN * 128;
        #pragma unroll
        for (int nt = 0; nt < 4; ++nt) {
            int tt = nt * 16 + ml;
            int c = 16 * wave + q * 4;
            half4 hv = *(const half4*)&X1[tt * GROW + c];  // tap1 = h_in(c,t)
            half4 o;
            #pragma unroll
            for (int r = 0; r < 4; ++r)
                o[r] = (_Float16)(racc[nt][r] + (float)hv[r]);
            *(half4*)&ho[(size_t)(t0 + tt) * 128 + c] = o;
        }
    }
}

// ---------------- last layer (l=29) + head, fused ----------------
// conv+GLU+skip of l=29, then z = relu(sacc + chunk) -> head X LDS directly,
// then z2 = relu(a_w z), logits = b_w z2. No chunk write, no res GEMM.
__global__ __launch_bounds__(512, 8) void last_head_kernel(
    const _Float16* __restrict__ h_in, const _Float16* __restrict__ chunk,
    float* __restrict__ out,
    const _Float16* __restrict__ cw, const float* __restrict__ cb,
    const _Float16* __restrict__ skw,
    const _Float16* __restrict__ aw, const float* __restrict__ ab,
    const _Float16* __restrict__ bw, const float* __restrict__ bb, int d) {
    __shared__ _Float16 SMEM[2 * TT * GROW];  // 34816 B; head X aliases (33792 B)
    _Float16* X0 = SMEM;
    _Float16* X1 = SMEM + TT * GROW;
    _Float16* G  = X0;  // alias: tap0 dead after conv reads
    _Float16* X  = SMEM; // head staging aliases whole SMEM after skip phase
    const int n = blockIdx.y, tb = blockIdx.x, t0 = tb * TT;
    const int tid = threadIdx.x;
    const int wave = __builtin_amdgcn_readfirstlane(tid >> 6);  // 0..7
    const int lane = tid & 63, q = lane >> 4, ml = lane & 15;

    // ---- stage both taps
    const _Float16* hn = h_in + (size_t)n * WLEN * 128;
    #pragma unroll
    for (int it = 0; it < 4; ++it) {
        int idx = it * 512 + tid;
        int seg = idx & 15;
        int rowc = (idx >> 4) & 63;
        int tap = idx >> 10;
        int src_t = t0 + rowc - (tap ? 0 : d);
        half8 v = (half8)(_Float16)0.0f;
        if (src_t >= 0)
            v = *(const half8*)&hn[(size_t)src_t * 128 + seg * 8];
        _Float16* Xb = tap ? X1 : X0;
        *(half8*)&Xb[rowc * GROW + seg * 8] = v;
    }
    __syncthreads();

    // ---- conv GEMM
    floatx4 acc[2][4];
    #pragma unroll
    for (int mt = 0; mt < 2; ++mt)
        #pragma unroll
        for (int r = 0; r < 4; ++r) {
            float bias = cb[32 * wave + mt * 16 + q * 4 + r];
            #pragma unroll
            for (int nt = 0; nt < 4; ++nt) acc[mt][nt][r] = bias;
        }
    #pragma unroll
    for (int hp = 0; hp < 2; ++hp) {
        const _Float16* Xb = hp ? X1 : X0;
        for (int ks = 0; ks < 4; ++ks) {
            half8 a[2];
            #pragma unroll
            for (int mt = 0; mt < 2; ++mt)
                a[mt] = *(const half8*)&cw[((((2 * wave + mt) * 8) + hp * 4 + ks) * 64 + lane) * 8];
            #pragma unroll
            for (int nt = 0; nt < 4; ++nt) {
                half8 b = *(const half8*)&Xb[(nt * 16 + ml) * GROW + ks * 32 + q * 8];
                #pragma unroll
                for (int mt = 0; mt < 2; ++mt)
                    acc[mt][nt] = __builtin_amdgcn_mfma_f32_16x16x32_f16(a[mt], b, acc[mt][nt], 0, 0, 0);
            }
        }
    }
    __syncthreads();

    // ---- GLU -> G
    #pragma unroll
    for (int mt = 0; mt < 2; ++mt)
        #pragma unroll
        for (int nt = 0; nt < 4; ++nt) {
            float g0 = acc[mt][nt][0] * sigmoidf_(acc[mt][nt][1]);
            float g1 = acc[mt][nt][2] * sigmoidf_(acc[mt][nt][3]);
            _Float16 p[2] = {(_Float16)g0, (_Float16)g1};
            *(uint32_t*)&G[(nt * 16 + ml) * GROW + 16 * wave + mt * 8 + 2 * q] = *(uint32_t*)p;
        }
    __syncthreads();

    // ---- skip GEMM + chunk read -> z = relu(sum) held in registers
    half4 z[2][4];
    {
        floatx4 sacc[2][4];
        #pragma unroll
        for (int mt = 0; mt < 2; ++mt)
            #pragma unroll
            for (int nt = 0; nt < 4; ++nt)
                #pragma unroll
                for (int r = 0; r < 4; ++r) sacc[mt][nt][r] = 0.0f;
        #pragma unroll
        for (int ks = 0; ks < 4; ++ks) {
            half8 a[2];
            #pragma unroll
            for (int mt = 0; mt < 2; ++mt)
                a[mt] = *(const half8*)&skw[((((2 * wave + mt) * 4) + ks) * 64 + lane) * 8];
            #pragma unroll
            for (int nt = 0; nt < 4; ++nt) {
                half8 b = *(const half8*)&G[(nt * 16 + ml) * GROW + ks * 32 + q * 8];
                #pragma unroll
                for (int mt = 0; mt < 2; ++mt)
                    sacc[mt][nt] = __builtin_amdgcn_mfma_f32_16x16x32_f16(a[mt], b, sacc[mt][nt], 0, 0, 0);
            }
        }
        const _Float16* cp = chunk + ((size_t)n * NTB + tb) * 16384;
        #pragma unroll
        for (int mt = 0; mt < 2; ++mt)
            #pragma unroll
            for (int nt = 0; nt < 4; ++nt) {
                size_t o = (size_t)((((wave * 2 + mt) * 4) + nt) * 64 + lane) * 4;
                half4 v = *(const half4*)&cp[o];
                #pragma unroll
                for (int r = 0; r < 4; ++r) {
                    // same value as old path: relu(f16(sacc+cold)) == f16(relu(sacc+cold))
                    _Float16 s = (_Float16)(sacc[mt][nt][r] + (float)v[r]);
                    z[mt][nt][r] = (_Float16)fmaxf((float)s, 0.0f);
                }
            }
    }
    __syncthreads();  // all G reads done before X overwrites SMEM

    // ---- z -> head X[t][s] (XROW layout)
    #pragma unroll
    for (int mt = 0; mt < 2; ++mt)
        #pragma unroll
        for (int nt = 0; nt < 4; ++nt)
            *(half4*)&X[(nt * 16 + ml) * XROW + 32 * wave + mt * 16 + q * 4] = z[mt][nt];
    __syncthreads();

    // ---- z2 = relu(a_w @ z + a_b)
    #pragma unroll
    for (int mt = 0; mt < 2; ++mt)
        #pragma unroll
        for (int r = 0; r < 4; ++r) {
            float bias = ab[32 * wave + mt * 16 + q * 4 + r];
            #pragma unroll
            for (int nt = 0; nt < 4; ++nt) acc[mt][nt][r] = bias;
        }
    for (int ks = 0; ks < 8; ++ks) {
        half8 a[2];
        #pragma unroll
        for (int mt = 0; mt < 2; ++mt)
            a[mt] = *(const half8*)&aw[((((2 * wave + mt) * 8) + ks) * 64 + lane) * 8];
        #pragma unroll
        for (int nt = 0; nt < 4; ++nt) {
            half8 b = *(const half8*)&X[(nt * 16 + ml) * XROW + ks * 32 + q * 8];
            #pragma unroll
            for (int mt = 0; mt < 2; ++mt)
                acc[mt][nt] = __builtin_amdgcn_mfma_f32_16x16x32_f16(a[mt], b, acc[mt][nt], 0, 0, 0);
        }
    }
    __syncthreads();
    #pragma unroll
    for (int mt = 0; mt < 2; ++mt)
        #pragma unroll
        for (int nt = 0; nt < 4; ++nt) {
            half4 zz;
            #pragma unroll
            for (int r = 0; r < 4; ++r)
                zz[r] = (_Float16)fmaxf(acc[mt][nt][r], 0.0f);
            *(half4*)&X[(nt * 16 + ml) * XROW + 32 * wave + mt * 16 + q * 4] = zz;
        }
    __syncthreads();

    // ---- logits = b_w @ z2 + b_b
    #pragma unroll
    for (int mt = 0; mt < 2; ++mt)
        #pragma unroll
        for (int r = 0; r < 4; ++r) {
            float bias = bb[32 * wave + mt * 16 + q * 4 + r];
            #pragma unroll
            for (int nt = 0; nt < 4; ++nt) acc[mt][nt][r] = bias;
        }
    for (int ks = 0; ks < 8; ++ks) {
        half8 a[2];
        #pragma unroll
        for (int mt = 0; mt < 2; ++mt)
            a[mt] = *(const half8*)&bw[((((2 * wave + mt) * 8) + ks) * 64 + lane) * 8];
        #pragma unroll
        for (int nt = 0; nt < 4; ++nt) {
            half8 b = *(const half8*)&X[(nt * 16 + ml) * XROW + ks * 32 + q * 8];
            #pragma unroll
            for (int mt = 0; mt < 2; ++mt)
                acc[mt][nt] = __builtin_amdgcn_mfma_f32_16x16x32_f16(a[mt], b, acc[mt][nt], 0, 0, 0);
        }
    }
    float* on = out + (size_t)n * S * WLEN;
    #pragma unroll
    for (int mt = 0; mt < 2; ++mt)
        #pragma unroll
        for (int nt = 0; nt < 4; ++nt)
            #pragma unroll
            for (int r = 0; r < 4; ++r) {
                int o = 32 * wave + mt * 16 + q * 4 + r;
                int tt = t0 + nt * 16 + ml;
                on[(size_t)o * WLEN + tt] = acc[mt][nt][r];
            }
}

extern "C" void kernel_launch(void* const* d_in, const int* in_sizes, int n_in,
                              void* d_out, int out_size, void* d_ws, size_t ws_size,
                              hipStream_t stream) {
    (void)in_sizes; (void)n_in; (void)out_size; (void)ws_size;
    const float* x       = (const float*)d_in[0];
    const float* w_shift = (const float*)d_in[1];
    const float* b_shift = (const float*)d_in[2];
    const float* conv_w  = (const float*)d_in[3];
    const float* conv_b  = (const float*)d_in[4];
    const float* res_w   = (const float*)d_in[5];
    const float* res_b   = (const float*)d_in[6];
    const float* skip_w  = (const float*)d_in[7];
    const float* skip_b  = (const float*)d_in[8];
    const float* a_w     = (const float*)d_in[9];
    const float* a_b     = (const float*)d_in[10];
    const float* b_w     = (const float*)d_in[11];
    const float* b_b     = (const float*)d_in[12];
    float* out = (float*)d_out;

    char* ws = (char*)d_ws;
    size_t off = 0;
    _Float16* hA    = (_Float16*)(ws + off); off += (size_t)NB * WLEN * 128 * 2;
    _Float16* hB    = (_Float16*)(ws + off); off += (size_t)NB * WLEN * 128 * 2;
    _Float16* chunk = (_Float16*)(ws + off); off += (size_t)NB * NTB * 16384 * 2;
    _Float16* cw  = (_Float16*)(ws + off); off += (size_t)NLAYERS * 256 * 256 * 2;
    _Float16* rsw = (_Float16*)(ws + off); off += (size_t)NLAYERS * 128 * 128 * 2;
    _Float16* skw = (_Float16*)(ws + off); off += (size_t)NLAYERS * 256 * 128 * 2;
    _Float16* aw  = (_Float16*)(ws + off); off += 256 * 256 * 2;
    _Float16* bw  = (_Float16*)(ws + off); off += 256 * 256 * 2;
    float* cbp  = (float*)(ws + off); off += (size_t)NLAYERS * 256 * 4;
    float* ssum = (float*)(ws + off); off += 256 * 4;
    // total ~74.3 MB

    prep_kernel<<<512, 256, 0, stream>>>(conv_w, res_w, skip_w, a_w, b_w,
                                         conv_b, skip_b,
                                         cw, rsw, skw, aw, bw, cbp, ssum);
    front_kernel<<<dim3(WLEN / 256, NB), 256, 0, stream>>>(x, w_shift, b_shift, hA);

    const dim3 grid(NTB, NB);
    _Float16* hin = hA;
    _Float16* hout = hB;
    for (int s = 0; s < 3; ++s) {
        const int l0 = s * 10;
        // stackA: layers l0..l0+3 (d=1,2,4,8), 80-row window
        if (s == 0)
            stack_kernel<0, 4, 5, 16, true><<<grid, 512, 0, stream>>>(
                hin, hout, chunk,
                cw + (size_t)l0 * 65536, cbp + l0 * 256,
                rsw + (size_t)l0 * 16384, res_b + l0 * 128,
                skw + (size_t)l0 * 32768, ssum);
        else
            stack_kernel<0, 4, 5, 16, false><<<grid, 512, 0, stream>>>(
                hin, hout, chunk,
                cw + (size_t)l0 * 65536, cbp + l0 * 256,
                rsw + (size_t)l0 * 16384, res_b + l0 * 128,
                skw + (size_t)l0 * 32768, ssum);
        { _Float16* tmp = hin; hin = hout; hout = tmp; }
        // single layers l0+4 .. l0+9 (d = 16..512); l=29 fused with head
        for (int jj = 4; jj < 10; ++jj) {
            const int l = l0 + jj;
            const int dil = 1 << jj;
            if (l == NLAYERS - 1) {
                last_head_kernel<<<grid, 512, 0, stream>>>(
                    hin, chunk, out,
                    cw + (size_t)l * 65536, cbp + l * 256,
                    skw + (size_t)l * 32768,
                    aw, a_b, bw, b_b, dil);
            } else {
                layer_kernel<<<grid, 512, 0, stream>>>(
                    hin, hout, chunk,
                    cw + (size_t)l * 65536, cbp + l * 256,
                    rsw + (size_t)l * 16384, res_b + l * 128,
                    skw + (size_t)l * 32768, dil);
                _Float16* tmp = hin; hin = hout; hout = tmp;
            }
        }
    }
}